// Round 3
// baseline (1594.066 us; speedup 1.0000x reference)
//
#include <hip/hip_runtime.h>
#include <math.h>

#define VEC   300
#define HID   256
#define ATT   500
#define NB    64
#define NS    128
#define G3    768     // 3*HID
#define GIC   1536    // both directions packed
#define H2    512     // 2*HID

typedef _Float16 half1;
typedef _Float16 h2_t __attribute__((ext_vector_type(2)));

__device__ __forceinline__ float sigm(float x){ return 1.0f/(1.0f+expf(-x)); }

// ---- prep: pack Whh into per-thread fp16 pair layout.
// Wpk[((dir*32+p)*3+j)*1024 + t] = {W[(j*256+u)*256 + ks*64+2p], W[... +2p+1]}
// where u=t&255, ks=t>>6... (ks = t>>8), k pairs p in [0,32).
__global__ __launch_bounds__(256) void k_prep(const float* __restrict__ Wf,
                       const float* __restrict__ Wb, h2_t* __restrict__ Wpk){
  int o = blockIdx.x*256 + threadIdx.x;    // < 2*32*3*1024 = 196608
  int t = o & 1023;
  int rest = o >> 10;                      // dir*96 + p*3 + j
  int j = rest % 3;
  int p = (rest/3) & 31;
  int dir = rest / 96;
  int u = t & 255, ks = t >> 8;
  const float* W = dir ? Wb : Wf;
  int k0 = ks*64 + 2*p;
  h2_t w;
  w.x = (half1)W[(j*HID+u)*HID + k0];
  w.y = (half1)W[(j*HID+u)*HID + k0 + 1];
  Wpk[o] = w;
}

// ---- input projection GEMM with fused embedding gather (fp32, unchanged).
#define BM 64
#define BN 128
#define BK 64
__global__ __launch_bounds__(256) void k_gi(const int* __restrict__ x,
      const float* __restrict__ emb,
      const float* __restrict__ Wf, const float* __restrict__ Wb,
      const float* __restrict__ bf, const float* __restrict__ bb,
      float* __restrict__ gi){
  __shared__ float As[BK][BM+4];
  __shared__ float Bs[BK][BN+4];
  __shared__ int   xi[BM];
  const int t = threadIdx.x;
  const int row0 = blockIdx.x * BM;
  const int col0 = blockIdx.y * BN;
  if (t < BM) {
    int i = row0 + t; int s = i >> 6; int b = i & 63;
    xi[t] = x[b*NS + s];
  }
  __syncthreads();
  float acc[4][8];
#pragma unroll
  for (int i = 0; i < 4; ++i)
#pragma unroll
    for (int j = 0; j < 8; ++j) acc[i][j] = 0.f;

  const int ty = t >> 4, tx = t & 15;
  for (int ks = 0; ks < 320; ks += BK) {
#pragma unroll
    for (int l = 0; l < 16; ++l) {
      int idx = l*256 + t;
      int r = idx >> 6, k = idx & 63;
      int kk = ks + k;
      As[k][r] = (kk < VEC) ? emb[(long)xi[r]*VEC + kk] : 0.f;
    }
#pragma unroll
    for (int l = 0; l < 32; ++l) {
      int idx = l*256 + t;
      int c = idx >> 6, k = idx & 63;
      int kk = ks + k;
      int g = col0 + c;
      float v = 0.f;
      if (kk < VEC) v = (g < G3) ? Wf[(long)g*VEC + kk] : Wb[(long)(g-G3)*VEC + kk];
      Bs[k][c] = v;
    }
    __syncthreads();
#pragma unroll 8
    for (int k = 0; k < BK; ++k) {
      float4 a4 = *reinterpret_cast<const float4*>(&As[k][ty*4]);
      float4 b0 = *reinterpret_cast<const float4*>(&Bs[k][tx*8]);
      float4 b1 = *reinterpret_cast<const float4*>(&Bs[k][tx*8+4]);
      float a[4] = {a4.x, a4.y, a4.z, a4.w};
      float bv[8] = {b0.x,b0.y,b0.z,b0.w,b1.x,b1.y,b1.z,b1.w};
#pragma unroll
      for (int i = 0; i < 4; ++i)
#pragma unroll
        for (int j = 0; j < 8; ++j) acc[i][j] += a[i]*bv[j];
    }
    __syncthreads();
  }
#pragma unroll
  for (int i = 0; i < 4; ++i) {
    int r = row0 + ty*4 + i;
#pragma unroll
    for (int j = 0; j < 8; ++j) {
      int g = col0 + tx*8 + j;
      float bias = (g < G3) ? bf[g] : bb[g-G3];
      gi[(long)r*GIC + g] = acc[i][j] + bias;
    }
  }
}

// ---- GRU scan: weights CU-resident. One WG = 1024 thr = 256 units x 4 k-slices,
// one (batch, dir) per WG -> 128 WGs. fp16 weights: 24 k-pairs in VGPRs + 8 in LDS.
__global__ __launch_bounds__(1024) void k_scan(const float* __restrict__ gi,
     const h2_t* __restrict__ Wpk,
     const float* __restrict__ bhf, const float* __restrict__ bhb,
     float* __restrict__ hseq){
  __shared__ float hl[260];
  __shared__ float part[256*13];       // [u][ks*3+j], pad 13
  __shared__ h2_t  lds_w[24*1024];     // [(p_loc*3+j)][t]  96KB
  const int t   = threadIdx.x;
  const int u   = t & 255;
  const int ks  = t >> 8;
  const int kb  = ks * 64;
  const int dir = blockIdx.x & 1;
  const int b   = blockIdx.x >> 1;
  const float* bhh = dir ? bhb : bhf;

  // one-time: 24 pairs x 3 gates -> registers (72 VGPRs of packed f16x2)
  h2_t wreg[24][3];
  const h2_t* wp = Wpk + (long)dir*96*1024 + t;
#pragma unroll
  for (int p = 0; p < 24; ++p)
#pragma unroll
    for (int j = 0; j < 3; ++j)
      wreg[p][j] = wp[(p*3+j)*1024];
  // one-time: last 8 pairs x 3 gates -> LDS
#pragma unroll
  for (int q = 0; q < 24; ++q)
    lds_w[q*1024 + t] = wp[(72+q)*1024];

  float bh0=0.f, bh1=0.f, bh2=0.f;
  if (ks == 0) { bh0 = bhh[u]; bh1 = bhh[HID+u]; bh2 = bhh[2*HID+u]; }
  if (t < 256) hl[t] = 0.f;
  __syncthreads();

#pragma unroll 1
  for (int tt = 0; tt < NS; ++tt) {
    const int s = dir ? (NS-1-tt) : tt;
    float i0=0.f, i1=0.f, i2=0.f;
    if (ks == 0) {                       // issue early; consumed after barrier
      long base = ((long)s*NB + b)*GIC + dir*G3 + u;
      i0 = gi[base]; i1 = gi[base+HID]; i2 = gi[base+2*HID];
    }
    float a0=0.f, a1=0.f, a2=0.f;
#pragma unroll
    for (int p = 0; p < 24; p += 2) {    // register-resident 48 rows
      float4 h4 = *reinterpret_cast<const float4*>(&hl[kb + 2*p]);
      a0 += (float)wreg[p][0].x*h4.x + (float)wreg[p][0].y*h4.y
          + (float)wreg[p+1][0].x*h4.z + (float)wreg[p+1][0].y*h4.w;
      a1 += (float)wreg[p][1].x*h4.x + (float)wreg[p][1].y*h4.y
          + (float)wreg[p+1][1].x*h4.z + (float)wreg[p+1][1].y*h4.w;
      a2 += (float)wreg[p][2].x*h4.x + (float)wreg[p][2].y*h4.y
          + (float)wreg[p+1][2].x*h4.z + (float)wreg[p+1][2].y*h4.w;
    }
#pragma unroll
    for (int p = 0; p < 8; p += 2) {     // LDS-resident 16 rows
      float4 h4 = *reinterpret_cast<const float4*>(&hl[kb + 48 + 2*p]);
      h2_t w00 = lds_w[(p*3+0)*1024 + t];
      h2_t w01 = lds_w[(p*3+1)*1024 + t];
      h2_t w02 = lds_w[(p*3+2)*1024 + t];
      h2_t w10 = lds_w[((p+1)*3+0)*1024 + t];
      h2_t w11 = lds_w[((p+1)*3+1)*1024 + t];
      h2_t w12 = lds_w[((p+1)*3+2)*1024 + t];
      a0 += (float)w00.x*h4.x + (float)w00.y*h4.y + (float)w10.x*h4.z + (float)w10.y*h4.w;
      a1 += (float)w01.x*h4.x + (float)w01.y*h4.y + (float)w11.x*h4.z + (float)w11.y*h4.w;
      a2 += (float)w02.x*h4.x + (float)w02.y*h4.y + (float)w12.x*h4.z + (float)w12.y*h4.w;
    }
    part[u*13 + ks*3 + 0] = a0;
    part[u*13 + ks*3 + 1] = a1;
    part[u*13 + ks*3 + 2] = a2;
    __syncthreads();
    if (ks == 0) {
      float g0 = bh0 + part[u*13+0] + part[u*13+3] + part[u*13+6] + part[u*13+9];
      float g1 = bh1 + part[u*13+1] + part[u*13+4] + part[u*13+7] + part[u*13+10];
      float g2 = bh2 + part[u*13+2] + part[u*13+5] + part[u*13+8] + part[u*13+11];
      float hc = hl[u];
      float r  = sigm(i0 + g0);
      float zg = sigm(i1 + g1);
      float n  = tanhf(i2 + r*g2);
      float hn = (1.f - zg)*n + zg*hc;
      hl[u] = hn;
      hseq[((long)b*NS + s)*H2 + dir*HID + u] = hn;
    }
    __syncthreads();
  }
}

// ---- attention scores u[b][s] = sum_a tanh(h.W_a + ab_a) * aw[z[b]][a]
__global__ __launch_bounds__(256) void k_att1(const float* __restrict__ hseq,
    const float* __restrict__ afW, const float* __restrict__ afb,
    const float* __restrict__ attw, const int* __restrict__ z,
    float* __restrict__ ub){
  __shared__ float ht[16][H2];
  __shared__ float red[16][260];
  const int t  = threadIdx.x;
  const int b  = blockIdx.x >> 3;
  const int s0 = (blockIdx.x & 7) * 16;
#pragma unroll
  for (int l = 0; l < 32; ++l) {
    int idx = l*256 + t; int sr = idx >> 9; int c = idx & 511;
    ht[sr][c] = hseq[((long)b*NS + s0+sr)*H2 + c];
  }
  __syncthreads();
  float us[16];
#pragma unroll
  for (int s = 0; s < 16; ++s) us[s] = 0.f;
  const int zb = z[b];
  for (int rep = 0; rep < 2; ++rep) {
    int a = rep*256 + t;
    if (a < ATT) {
      const float* wr = afW + (long)a*H2;
      float ab = afb[a];
      float aw = attw[zb*ATT + a];
      float d[16];
#pragma unroll
      for (int s = 0; s < 16; ++s) d[s] = ab;
      for (int h = 0; h < H2; h += 4) {
        float4 w4 = *reinterpret_cast<const float4*>(wr + h);
#pragma unroll
        for (int s = 0; s < 16; ++s) {
          float4 hv = *reinterpret_cast<const float4*>(&ht[s][h]);
          d[s] += w4.x*hv.x + w4.y*hv.y + w4.z*hv.z + w4.w*hv.w;
        }
      }
#pragma unroll
      for (int s = 0; s < 16; ++s) us[s] += tanhf(d[s]) * aw;
    }
  }
#pragma unroll
  for (int s = 0; s < 16; ++s) red[s][t] = us[s];
  __syncthreads();
  for (int off = 128; off >= 1; off >>= 1) {
    if (t < off) {
#pragma unroll
      for (int s = 0; s < 16; ++s) red[s][t] += red[s][t+off];
    }
    __syncthreads();
  }
  if (t < 16) ub[b*NS + s0 + t] = red[t][0];
}

// ---- softmax + pooled + fc
__global__ __launch_bounds__(256) void k_att2(const float* __restrict__ hseq,
   const float* __restrict__ ub, const float* __restrict__ fcW,
   const float* __restrict__ fcb, float* __restrict__ out){
  __shared__ float att[NS];
  __shared__ float red[256];
  __shared__ float pool[H2];
  const int t = threadIdx.x, b = blockIdx.x;
  float v = (t < NS) ? ub[b*NS + t] : -3.4e38f;
  red[t] = v; __syncthreads();
  for (int off = 128; off >= 1; off >>= 1) {
    if (t < off) red[t] = fmaxf(red[t], red[t+off]);
    __syncthreads();
  }
  float mx = red[0]; __syncthreads();
  float e = (t < NS) ? expf(v - mx) : 0.f;
  red[t] = e; __syncthreads();
  for (int off = 128; off >= 1; off >>= 1) {
    if (t < off) red[t] += red[t+off];
    __syncthreads();
  }
  float sm = red[0]; __syncthreads();
  if (t < NS) att[t] = e / sm;
  __syncthreads();
#pragma unroll
  for (int rep = 0; rep < 2; ++rep) {
    int c = rep*256 + t;
    float acc = 0.f;
#pragma unroll 4
    for (int s = 0; s < NS; ++s) acc += att[s] * hseq[((long)b*NS + s)*H2 + c];
    pool[c] = acc;
  }
  __syncthreads();
  for (int j = 0; j < 2; ++j) {
    float p = pool[t]*fcW[j*H2+t] + pool[t+256]*fcW[j*H2+t+256];
    red[t] = p; __syncthreads();
    for (int off = 128; off >= 1; off >>= 1) {
      if (t < off) red[t] += red[t+off];
      __syncthreads();
    }
    if (t == 0) out[b*2+j] = red[0] + fcb[j];
    __syncthreads();
  }
}

extern "C" void kernel_launch(void* const* d_in, const int* in_sizes, int n_in,
                              void* d_out, int out_size, void* d_ws, size_t ws_size,
                              hipStream_t stream) {
  const int*   x     = (const int*)  d_in[0];
  const int*   z     = (const int*)  d_in[1];
  const float* emb   = (const float*)d_in[2];
  const float* Wih_f = (const float*)d_in[3];
  const float* Whh_f = (const float*)d_in[4];
  const float* bih_f = (const float*)d_in[5];
  const float* bhh_f = (const float*)d_in[6];
  const float* Wih_b = (const float*)d_in[7];
  const float* Whh_b = (const float*)d_in[8];
  const float* bih_b = (const float*)d_in[9];
  const float* bhh_b = (const float*)d_in[10];
  const float* afW   = (const float*)d_in[11];
  const float* afb   = (const float*)d_in[12];
  const float* attw  = (const float*)d_in[13];
  const float* fcW   = (const float*)d_in[14];
  const float* fcb   = (const float*)d_in[15];

  float* ws   = (float*)d_ws;
  h2_t* Wpk   = (h2_t*)ws;               // 196608 x 4B
  float* giW  = ws   + 196608;           // 8192*1536 = 12582912
  float* hseq = giW  + 12582912;         // 64*128*512 = 4194304
  float* ubuf = hseq + 4194304;          // 64*128

  k_prep<<<dim3(768), dim3(256), 0, stream>>>(Whh_f, Whh_b, Wpk);
  k_gi  <<<dim3(128,12), dim3(256), 0, stream>>>(x, emb, Wih_f, Wih_b, bih_f, bih_b, giW);
  k_scan<<<dim3(128),  dim3(1024), 0, stream>>>(giW, Wpk, bhh_f, bhh_b, hseq);
  k_att1<<<dim3(512),  dim3(256), 0, stream>>>(hseq, afW, afb, attw, z, ubuf);
  k_att2<<<dim3(64),   dim3(256), 0, stream>>>(hseq, ubuf, fcW, fcb, (float*)d_out);
}

// Round 4
// 1584.810 us; speedup vs baseline: 1.0058x; 1.0058x over previous
//
#include <hip/hip_runtime.h>
#include <math.h>

#define VEC   300
#define HID   256
#define ATT   500
#define NB    64
#define NS    128
#define G3    768     // 3*HID
#define GIC   1536    // both directions packed
#define H2    512     // 2*HID

typedef _Float16 half1;
typedef _Float16 h2_t __attribute__((ext_vector_type(2)));

__device__ __forceinline__ float sigm(float x){ return 1.0f/(1.0f+expf(-x)); }

// ---- prep: pack Whh into per-thread fp16 pair layout.
// Wpk[((dir*32+p)*3+j)*1024 + t] = {W[(j*256+u)*256 + ks*64+2p], W[... +2p+1]}
// where u=t&255, ks=t>>8, k pairs p in [0,32).
__global__ __launch_bounds__(256) void k_prep(const float* __restrict__ Wf,
                       const float* __restrict__ Wb, h2_t* __restrict__ Wpk){
  int o = blockIdx.x*256 + threadIdx.x;    // < 2*32*3*1024 = 196608
  int t = o & 1023;
  int rest = o >> 10;                      // dir*96 + p*3 + j
  int j = rest % 3;
  int p = (rest/3) & 31;
  int dir = rest / 96;
  int u = t & 255, ks = t >> 8;
  const float* W = dir ? Wb : Wf;
  int k0 = ks*64 + 2*p;
  h2_t w;
  w.x = (half1)W[(j*HID+u)*HID + k0];
  w.y = (half1)W[(j*HID+u)*HID + k0 + 1];
  Wpk[o] = w;
}

// ---- input projection GEMM with fused embedding gather (fp32, unchanged).
#define BM 64
#define BN 128
#define BK 64
__global__ __launch_bounds__(256) void k_gi(const int* __restrict__ x,
      const float* __restrict__ emb,
      const float* __restrict__ Wf, const float* __restrict__ Wb,
      const float* __restrict__ bf, const float* __restrict__ bb,
      float* __restrict__ gi){
  __shared__ float As[BK][BM+4];
  __shared__ float Bs[BK][BN+4];
  __shared__ int   xi[BM];
  const int t = threadIdx.x;
  const int row0 = blockIdx.x * BM;
  const int col0 = blockIdx.y * BN;
  if (t < BM) {
    int i = row0 + t; int s = i >> 6; int b = i & 63;
    xi[t] = x[b*NS + s];
  }
  __syncthreads();
  float acc[4][8];
#pragma unroll
  for (int i = 0; i < 4; ++i)
#pragma unroll
    for (int j = 0; j < 8; ++j) acc[i][j] = 0.f;

  const int ty = t >> 4, tx = t & 15;
  for (int ks = 0; ks < 320; ks += BK) {
#pragma unroll
    for (int l = 0; l < 16; ++l) {
      int idx = l*256 + t;
      int r = idx >> 6, k = idx & 63;
      int kk = ks + k;
      As[k][r] = (kk < VEC) ? emb[(long)xi[r]*VEC + kk] : 0.f;
    }
#pragma unroll
    for (int l = 0; l < 32; ++l) {
      int idx = l*256 + t;
      int c = idx >> 6, k = idx & 63;
      int kk = ks + k;
      int g = col0 + c;
      float v = 0.f;
      if (kk < VEC) v = (g < G3) ? Wf[(long)g*VEC + kk] : Wb[(long)(g-G3)*VEC + kk];
      Bs[k][c] = v;
    }
    __syncthreads();
#pragma unroll 8
    for (int k = 0; k < BK; ++k) {
      float4 a4 = *reinterpret_cast<const float4*>(&As[k][ty*4]);
      float4 b0 = *reinterpret_cast<const float4*>(&Bs[k][tx*8]);
      float4 b1 = *reinterpret_cast<const float4*>(&Bs[k][tx*8+4]);
      float a[4] = {a4.x, a4.y, a4.z, a4.w};
      float bv[8] = {b0.x,b0.y,b0.z,b0.w,b1.x,b1.y,b1.z,b1.w};
#pragma unroll
      for (int i = 0; i < 4; ++i)
#pragma unroll
        for (int j = 0; j < 8; ++j) acc[i][j] += a[i]*bv[j];
    }
    __syncthreads();
  }
#pragma unroll
  for (int i = 0; i < 4; ++i) {
    int r = row0 + ty*4 + i;
#pragma unroll
    for (int j = 0; j < 8; ++j) {
      int g = col0 + tx*8 + j;
      float bias = (g < G3) ? bf[g] : bb[g-G3];
      gi[(long)r*GIC + g] = acc[i][j] + bias;
    }
  }
}

// ---- GRU scan: weights CU-resident. One WG = 1024 thr = 256 units x 4 k-slices,
// one (batch, dir) per WG -> 128 WGs. fp16 weights: 24 k-pairs in VGPRs + 8 in LDS.
// launch_bounds(1024, 4): 4 waves/SIMD -> 128-VGPR cap so wreg[24][3] stays in registers.
__global__ __launch_bounds__(1024, 4) void k_scan(const float* __restrict__ gi,
     const h2_t* __restrict__ Wpk,
     const float* __restrict__ bhf, const float* __restrict__ bhb,
     float* __restrict__ hseq){
  __shared__ float hl[260];
  __shared__ float part[256*13];       // [u][ks*3+j], pad 13
  __shared__ h2_t  lds_w[24*1024];     // [(p_loc*3+j)][t]  96KB
  const int t   = threadIdx.x;
  const int u   = t & 255;
  const int ks  = t >> 8;
  const int kb  = ks * 64;
  const int dir = blockIdx.x & 1;
  const int b   = blockIdx.x >> 1;
  const float* bhh = dir ? bhb : bhf;

  // one-time: 24 pairs x 3 gates -> registers (72 VGPRs of packed f16x2)
  h2_t wreg[24][3];
  const h2_t* wp = Wpk + (long)dir*96*1024 + t;
#pragma unroll
  for (int p = 0; p < 24; ++p)
#pragma unroll
    for (int j = 0; j < 3; ++j)
      wreg[p][j] = wp[(p*3+j)*1024];
  // one-time: last 8 pairs x 3 gates -> LDS
#pragma unroll
  for (int q = 0; q < 24; ++q)
    lds_w[q*1024 + t] = wp[(72+q)*1024];

  float bh0=0.f, bh1=0.f, bh2=0.f;
  if (ks == 0) { bh0 = bhh[u]; bh1 = bhh[HID+u]; bh2 = bhh[2*HID+u]; }
  if (t < 256) hl[t] = 0.f;
  __syncthreads();

#pragma unroll 1
  for (int tt = 0; tt < NS; ++tt) {
    const int s = dir ? (NS-1-tt) : tt;
    float i0=0.f, i1=0.f, i2=0.f;
    if (ks == 0) {                       // wave-uniform branch; issued early
      long base = ((long)s*NB + b)*GIC + dir*G3 + u;
      i0 = gi[base]; i1 = gi[base+HID]; i2 = gi[base+2*HID];
    }
    float a0=0.f, a1=0.f, a2=0.f;
#pragma unroll
    for (int p = 0; p < 24; p += 2) {    // register-resident 48 rows
      float4 h4 = *reinterpret_cast<const float4*>(&hl[kb + 2*p]);
      a0 += (float)wreg[p][0].x*h4.x + (float)wreg[p][0].y*h4.y
          + (float)wreg[p+1][0].x*h4.z + (float)wreg[p+1][0].y*h4.w;
      a1 += (float)wreg[p][1].x*h4.x + (float)wreg[p][1].y*h4.y
          + (float)wreg[p+1][1].x*h4.z + (float)wreg[p+1][1].y*h4.w;
      a2 += (float)wreg[p][2].x*h4.x + (float)wreg[p][2].y*h4.y
          + (float)wreg[p+1][2].x*h4.z + (float)wreg[p+1][2].y*h4.w;
    }
#pragma unroll
    for (int p = 0; p < 8; p += 2) {     // LDS-resident 16 rows
      float4 h4 = *reinterpret_cast<const float4*>(&hl[kb + 48 + 2*p]);
      h2_t w00 = lds_w[(p*3+0)*1024 + t];
      h2_t w01 = lds_w[(p*3+1)*1024 + t];
      h2_t w02 = lds_w[(p*3+2)*1024 + t];
      h2_t w10 = lds_w[((p+1)*3+0)*1024 + t];
      h2_t w11 = lds_w[((p+1)*3+1)*1024 + t];
      h2_t w12 = lds_w[((p+1)*3+2)*1024 + t];
      a0 += (float)w00.x*h4.x + (float)w00.y*h4.y + (float)w10.x*h4.z + (float)w10.y*h4.w;
      a1 += (float)w01.x*h4.x + (float)w01.y*h4.y + (float)w11.x*h4.z + (float)w11.y*h4.w;
      a2 += (float)w02.x*h4.x + (float)w02.y*h4.y + (float)w12.x*h4.z + (float)w12.y*h4.w;
    }
    part[u*13 + ks*3 + 0] = a0;
    part[u*13 + ks*3 + 1] = a1;
    part[u*13 + ks*3 + 2] = a2;
    __syncthreads();
    if (ks == 0) {
      float g0 = bh0 + part[u*13+0] + part[u*13+3] + part[u*13+6] + part[u*13+9];
      float g1 = bh1 + part[u*13+1] + part[u*13+4] + part[u*13+7] + part[u*13+10];
      float g2 = bh2 + part[u*13+2] + part[u*13+5] + part[u*13+8] + part[u*13+11];
      float hc = hl[u];
      float r  = sigm(i0 + g0);
      float zg = sigm(i1 + g1);
      float n  = tanhf(i2 + r*g2);
      float hn = (1.f - zg)*n + zg*hc;
      hl[u] = hn;
      hseq[((long)b*NS + s)*H2 + dir*HID + u] = hn;
    }
    __syncthreads();
  }
}

// ---- attention scores u[b][s] = sum_a tanh(h.W_a + ab_a) * aw[z[b]][a]
__global__ __launch_bounds__(256) void k_att1(const float* __restrict__ hseq,
    const float* __restrict__ afW, const float* __restrict__ afb,
    const float* __restrict__ attw, const int* __restrict__ z,
    float* __restrict__ ub){
  __shared__ float ht[16][H2];
  __shared__ float red[16][260];
  const int t  = threadIdx.x;
  const int b  = blockIdx.x >> 3;
  const int s0 = (blockIdx.x & 7) * 16;
#pragma unroll
  for (int l = 0; l < 32; ++l) {
    int idx = l*256 + t; int sr = idx >> 9; int c = idx & 511;
    ht[sr][c] = hseq[((long)b*NS + s0+sr)*H2 + c];
  }
  __syncthreads();
  float us[16];
#pragma unroll
  for (int s = 0; s < 16; ++s) us[s] = 0.f;
  const int zb = z[b];
  for (int rep = 0; rep < 2; ++rep) {
    int a = rep*256 + t;
    if (a < ATT) {
      const float* wr = afW + (long)a*H2;
      float ab = afb[a];
      float aw = attw[zb*ATT + a];
      float d[16];
#pragma unroll
      for (int s = 0; s < 16; ++s) d[s] = ab;
      for (int h = 0; h < H2; h += 4) {
        float4 w4 = *reinterpret_cast<const float4*>(wr + h);
#pragma unroll
        for (int s = 0; s < 16; ++s) {
          float4 hv = *reinterpret_cast<const float4*>(&ht[s][h]);
          d[s] += w4.x*hv.x + w4.y*hv.y + w4.z*hv.z + w4.w*hv.w;
        }
      }
#pragma unroll
      for (int s = 0; s < 16; ++s) us[s] += tanhf(d[s]) * aw;
    }
  }
#pragma unroll
  for (int s = 0; s < 16; ++s) red[s][t] = us[s];
  __syncthreads();
  for (int off = 128; off >= 1; off >>= 1) {
    if (t < off) {
#pragma unroll
      for (int s = 0; s < 16; ++s) red[s][t] += red[s][t+off];
    }
    __syncthreads();
  }
  if (t < 16) ub[b*NS + s0 + t] = red[t][0];
}

// ---- softmax + pooled + fc
__global__ __launch_bounds__(256) void k_att2(const float* __restrict__ hseq,
   const float* __restrict__ ub, const float* __restrict__ fcW,
   const float* __restrict__ fcb, float* __restrict__ out){
  __shared__ float att[NS];
  __shared__ float red[256];
  __shared__ float pool[H2];
  const int t = threadIdx.x, b = blockIdx.x;
  float v = (t < NS) ? ub[b*NS + t] : -3.4e38f;
  red[t] = v; __syncthreads();
  for (int off = 128; off >= 1; off >>= 1) {
    if (t < off) red[t] = fmaxf(red[t], red[t+off]);
    __syncthreads();
  }
  float mx = red[0]; __syncthreads();
  float e = (t < NS) ? expf(v - mx) : 0.f;
  red[t] = e; __syncthreads();
  for (int off = 128; off >= 1; off >>= 1) {
    if (t < off) red[t] += red[t+off];
    __syncthreads();
  }
  float sm = red[0]; __syncthreads();
  if (t < NS) att[t] = e / sm;
  __syncthreads();
#pragma unroll
  for (int rep = 0; rep < 2; ++rep) {
    int c = rep*256 + t;
    float acc = 0.f;
#pragma unroll 4
    for (int s = 0; s < NS; ++s) acc += att[s] * hseq[((long)b*NS + s)*H2 + c];
    pool[c] = acc;
  }
  __syncthreads();
  for (int j = 0; j < 2; ++j) {
    float p = pool[t]*fcW[j*H2+t] + pool[t+256]*fcW[j*H2+t+256];
    red[t] = p; __syncthreads();
    for (int off = 128; off >= 1; off >>= 1) {
      if (t < off) red[t] += red[t+off];
      __syncthreads();
    }
    if (t == 0) out[b*2+j] = red[0] + fcb[j];
    __syncthreads();
  }
}

extern "C" void kernel_launch(void* const* d_in, const int* in_sizes, int n_in,
                              void* d_out, int out_size, void* d_ws, size_t ws_size,
                              hipStream_t stream) {
  const int*   x     = (const int*)  d_in[0];
  const int*   z     = (const int*)  d_in[1];
  const float* emb   = (const float*)d_in[2];
  const float* Wih_f = (const float*)d_in[3];
  const float* Whh_f = (const float*)d_in[4];
  const float* bih_f = (const float*)d_in[5];
  const float* bhh_f = (const float*)d_in[6];
  const float* Wih_b = (const float*)d_in[7];
  const float* Whh_b = (const float*)d_in[8];
  const float* bih_b = (const float*)d_in[9];
  const float* bhh_b = (const float*)d_in[10];
  const float* afW   = (const float*)d_in[11];
  const float* afb   = (const float*)d_in[12];
  const float* attw  = (const float*)d_in[13];
  const float* fcW   = (const float*)d_in[14];
  const float* fcb   = (const float*)d_in[15];

  float* ws   = (float*)d_ws;
  h2_t* Wpk   = (h2_t*)ws;               // 196608 x 4B
  float* giW  = ws   + 196608;           // 8192*1536 = 12582912
  float* hseq = giW  + 12582912;         // 64*128*512 = 4194304
  float* ubuf = hseq + 4194304;          // 64*128

  k_prep<<<dim3(768), dim3(256), 0, stream>>>(Whh_f, Whh_b, Wpk);
  k_gi  <<<dim3(128,12), dim3(256), 0, stream>>>(x, emb, Wih_f, Wih_b, bih_f, bih_b, giW);
  k_scan<<<dim3(128),  dim3(1024), 0, stream>>>(giW, Wpk, bhh_f, bhh_b, hseq);
  k_att1<<<dim3(512),  dim3(256), 0, stream>>>(hseq, afW, afb, attw, z, ubuf);
  k_att2<<<dim3(64),   dim3(256), 0, stream>>>(hseq, ubuf, fcW, fcb, (float*)d_out);
}